// Round 1
// baseline (142.167 us; speedup 1.0000x reference)
//
#include <hip/hip_runtime.h>
#include <cfloat>
#include <cmath>

#define N_TOK (32*4096)                 // 131072 tokens
#define DIM   64
#define N_E   1024

typedef __attribute__((ext_vector_type(8))) __bf16 bf16x8;
typedef __attribute__((ext_vector_type(4))) float  f32x4;
typedef unsigned int u32;

// ws layout (bytes)
#define WS_CN2    0u                    // 1024 f32 (-0.5*||e||^2)           (4 KB)
#define WS_CBF    4096u                 // fragment-ordered bf16 hi+lo       (256 KB)
#define WS_GIDX   266240u               // 131072 int winner ids             (512 KB)
#define WS_COUNTS 790528u               // 1024 u32                          (4 KB)
#define WS_SSEA   794624u               // 64 f32 partial SSE cells
#define WS_DONE   794880u               // 1 u32

// async global->LDS, 16 B per lane; LDS dest must be wave-uniform base + lane*16
__device__ __forceinline__ void async_cp16(const void* g, void* l) {
    __builtin_amdgcn_global_load_lds((const __attribute__((address_space(1))) u32*)g,
                                     (__attribute__((address_space(3))) u32*)l, 16, 0, 0);
}

// Codebook -> MFMA B-fragment order (bf16 hi/lo), round-5 layout:
//   cbF[cblk*16384 + plane*8192 + ch*1024 + kf*512 + (q*16+n)*8 + j]
// 32 blocks x 256 threads; thread = (code, oct): coalesced loads/stores.
__global__ __launch_bounds__(256) void prep_kernel(const float* __restrict__ cb,
        float* __restrict__ cn2, __bf16* __restrict__ cbF,
        unsigned* __restrict__ counts, float* __restrict__ ssea, unsigned* __restrict__ done) {
    const int t = threadIdx.x;
    const int k = blockIdx.x * 32 + (t >> 3);        // code 0..1023
    const int oct = t & 7;
    if (t < 32) counts[blockIdx.x * 32 + t] = 0u;
    if (blockIdx.x == 0 && t < 64) ssea[t] = 0.f;
    if (blockIdx.x == 0 && t == 0) *done = 0u;

    const float4 a = *(const float4*)(cb + (size_t)k * DIM + oct * 8);
    const float4 b = *(const float4*)(cb + (size_t)k * DIM + oct * 8 + 4);
    float v[8] = {a.x,a.y,a.z,a.w,b.x,b.y,b.z,b.w};
    bf16x8 hv, lv;
    float nrm = 0.f;
#pragma unroll
    for (int j = 0; j < 8; ++j) {
        float f = v[j];
        nrm = fmaf(f, f, nrm);
        __bf16 h = (__bf16)f;
        __bf16 l = (__bf16)(f - (float)h);
        hv[j] = h; lv[j] = l;
    }
    const int cblk = k >> 7, local = k & 127;
    const int ch = local >> 4, n = local & 15;
    const int kf = oct >> 2, q = oct & 3;
    __bf16* base = cbF + (size_t)cblk * 16384 + ch * 1024 + kf * 512 + q * 128 + n * 8;
    *(bf16x8*)(base) = hv;
    *(bf16x8*)(base + 8192) = lv;
    nrm += __shfl_xor(nrm, 1, 64);
    nrm += __shfl_xor(nrm, 2, 64);
    nrm += __shfl_xor(nrm, 4, 64);
    if (oct == 0) cn2[k] = -0.5f * nrm;
}

// Round-6 shape: 1024 blocks x 128 tokens (32 tokens/wave, 2 A-tiles) -> 4
// blocks/CU (was grid-capped at 2). Codebook streamed as 16 x 64-code chunks
// (16 KB each), DOUBLE-buffered in LDS with counted s_waitcnt vmcnt(4): the
// prefetch for chunk c+1 stays in flight across the barrier (T3/T4-lite),
// never drained to 0 inside the loop. cn2 staged once into LDS at prologue.
__global__ __launch_bounds__(256, 4) void fused_kernel(const float* __restrict__ z,
        const __bf16* __restrict__ cbF, const float* __restrict__ cn2,
        const float* __restrict__ cb, float* __restrict__ out,
        int* __restrict__ gidx, float* __restrict__ ssea) {
    __shared__ __bf16 lbuf[2][8192];                 // 2 x 16 KB, fragment-ordered
    __shared__ float  lcn[1024];                     // all -0.5||e||^2 staged once
    __shared__ int    lidx[128];
    const int t    = threadIdx.x;
    const int lane = t & 63;
    const int w    = t >> 6;
    const int n    = lane & 15;                      // MFMA col / code-in-chunk
    const int q    = lane >> 4;                      // k-octet selector
    const int wtok = blockIdx.x * 128 + w * 32;

    // A fragments (32 tokens/wave as 2 tiles x 2 K-halves), bf16 hi/lo in regs.
    bf16x8 ah[2][2], al[2][2];
    float pn[2];
    const float4* z4 = (const float4*)z;
#pragma unroll
    for (int tile = 0; tile < 2; ++tile) {
        int tok = wtok + tile*16 + n;
        float nrm = 0.f;
#pragma unroll
        for (int kf = 0; kf < 2; ++kf) {
            float4 p0 = z4[(size_t)tok*16 + kf*8 + q*2];
            float4 p1 = z4[(size_t)tok*16 + kf*8 + q*2 + 1];
            float v[8] = {p0.x,p0.y,p0.z,p0.w,p1.x,p1.y,p1.z,p1.w};
            bf16x8 hv, lv;
#pragma unroll
            for (int j = 0; j < 8; ++j) {
                float f = v[j];
                nrm = fmaf(f, f, nrm);
                __bf16 h = (__bf16)f;
                __bf16 l = (__bf16)(f - (float)h);
                hv[j] = h; lv[j] = l;
            }
            ah[tile][kf] = hv; al[tile][kf] = lv;
        }
        nrm += __shfl_xor(nrm, 16, 64);
        nrm += __shfl_xor(nrm, 32, 64);
        pn[tile] = nrm;
    }

    // Stage chunk c: hi 8 KB -> lbuf bytes [0,8192), lo 8 KB -> [8192,16384).
    // Per wave: uniform base + lane*16 (global_load_lds constraint).
#define STAGE(c_, b_) do {                                                        \
        const char* hs_ = (const char*)cbF + ((c_) >> 1) * 32768 + ((c_) & 1) * 8192; \
        char* d_ = (char*)(&lbuf[(b_)][0]);                                       \
        const int o_ = t * 16;                                                    \
        async_cp16(hs_ + o_,         d_ + o_);                                    \
        async_cp16(hs_ + o_ + 4096,  d_ + o_ + 4096);                             \
        async_cp16(hs_ + o_ + 16384, d_ + o_ + 8192);                             \
        async_cp16(hs_ + o_ + 20480, d_ + o_ + 12288);                            \
    } while (0)

    async_cp16((const char*)cn2 + t * 16, (char*)lcn + t * 16);   // 4 KB cn2
    STAGE(0, 0);                                     // 5 VMEM ops outstanding

    float best[8];
#pragma unroll
    for (int s = 0; s < 8; ++s) best[s] = -3.4e38f;

#pragma unroll 2
    for (int c = 0; c < 16; ++c) {
        if (c < 15) STAGE(c + 1, (c + 1) & 1);       // prefetch next chunk (4 ops)
        if (c < 15) asm volatile("s_waitcnt vmcnt(4)" ::: "memory");   // prev chunk landed
        else        asm volatile("s_waitcnt vmcnt(0)" ::: "memory");   // last chunk: drain
        __builtin_amdgcn_s_barrier();                // all waves' stages visible
        __builtin_amdgcn_sched_barrier(0);           // no ds_read hoists above this
        const __bf16* bp = &lbuf[c & 1][0];
#pragma unroll
        for (int ch = 0; ch < 4; ++ch) {
            const int fb = ch*1024 + lane*8;         // conflict-free: lane*16 B
            bf16x8 bh0 = *(const bf16x8*)(bp + fb);
            bf16x8 bh1 = *(const bf16x8*)(bp + fb + 512);
            bf16x8 bl0 = *(const bf16x8*)(bp + 4096 + fb);
            bf16x8 bl1 = *(const bf16x8*)(bp + 4096 + fb + 512);
            const float cnv = lcn[(c << 6) + (ch << 4) + n];
            const u32 codebits = (u32)((c << 6) | (ch << 4) | n);
#pragma unroll
            for (int tile = 0; tile < 2; ++tile) {
                f32x4 acc = {cnv, cnv, cnv, cnv};
                acc = __builtin_amdgcn_mfma_f32_16x16x32_bf16(ah[tile][0], bh0, acc, 0, 0, 0);
                acc = __builtin_amdgcn_mfma_f32_16x16x32_bf16(ah[tile][1], bh1, acc, 0, 0, 0);
                acc = __builtin_amdgcn_mfma_f32_16x16x32_bf16(al[tile][0], bh0, acc, 0, 0, 0);
                acc = __builtin_amdgcn_mfma_f32_16x16x32_bf16(al[tile][1], bh1, acc, 0, 0, 0);
                acc = __builtin_amdgcn_mfma_f32_16x16x32_bf16(ah[tile][0], bl0, acc, 0, 0, 0);
                acc = __builtin_amdgcn_mfma_f32_16x16x32_bf16(ah[tile][1], bl1, acc, 0, 0, 0);
#pragma unroll
                for (int r = 0; r < 4; ++r) {
                    float packed = __uint_as_float((__float_as_uint(acc[r]) & 0xFFFFFC00u) | codebits);
                    best[tile*4 + r] = fmaxf(best[tile*4 + r], packed);
                }
            }
        }
        __builtin_amdgcn_sched_barrier(0);           // ds_reads/MFMAs stay above
        __builtin_amdgcn_s_barrier();                // buffer free for next STAGE
    }
#undef STAGE

    // Winner reduce; ids -> wave-local LDS then plain coalesced store.
    float sse_acc = 0.f;
#pragma unroll
    for (int s = 0; s < 8; ++s) {
        float bs = best[s];
#pragma unroll
        for (int m = 8; m >= 1; m >>= 1)
            bs = fmaxf(bs, __shfl_xor(bs, m, 64));
        u32 bits = __float_as_uint(bs);
        int id = (int)(bits & 0x3FFu);
        float sc = __uint_as_float(bits & 0xFFFFFC00u);
        float nrm = __shfl(pn[s >> 2], (q << 2) | (s & 3), 64);
        if (n == 0) {
            lidx[w*32 + (s >> 2)*16 + q*4 + (s & 3)] = id;
            sse_acc += fmaf(-2.f, sc, nrm);          // d = ||z||^2 - 2*score
        }
    }
    sse_acc += __shfl_xor(sse_acc, 16, 64);
    sse_acc += __shfl_xor(sse_acc, 32, 64);
    if (lane == 0) atomicAdd(&ssea[(blockIdx.x*4 + w) & 63], sse_acc);

    int myid = lidx[w*32 + (lane & 31)];             // wave-local LDS, no barrier
    if (lane < 32) gidx[wtok + lane] = myid;         // coalesced id publish

    // z_q write: wave's 32 tokens, readlane id -> independent coalesced row copies.
    const size_t obase = 1 + (size_t)wtok * DIM;
#pragma unroll
    for (int i = 0; i < 32; ++i) {
        int id = __shfl(myid, i, 64);                // compile-time lane -> v_readlane
        float qv = cb[(size_t)id * DIM + lane];
        out[obase + (size_t)i * DIM + lane] = qv;
    }
}

// Histogram from gidx via per-block LDS counts (LDS atomics), then 32 spread
// global adds per cell; last block computes entropy + loss.
__global__ __launch_bounds__(256) void hist_kernel(const int* __restrict__ gidx,
        unsigned* __restrict__ counts, const float* __restrict__ ssea,
        unsigned* __restrict__ done, float* __restrict__ out) {
    __shared__ unsigned hist[1024];
    __shared__ float fred[4];
    __shared__ u32 lastflag;
    const int t = threadIdx.x;
#pragma unroll
    for (int i = 0; i < 4; ++i) hist[t + 256*i] = 0u;
    __syncthreads();
    const int base = blockIdx.x * 4096;
#pragma unroll
    for (int i = 0; i < 16; ++i) {
        int id = gidx[base + i*256 + t];
        atomicAdd(&hist[id], 1u);
    }
    __syncthreads();
#pragma unroll
    for (int i = 0; i < 4; ++i) {
        unsigned v = hist[t + 256*i];
        if (v) atomicAdd(&counts[t + 256*i], v);
    }
    __threadfence();
    __syncthreads();
    if (t == 0) lastflag = (atomicAdd(done, 1u) == 31u) ? 1u : 0u;
    __syncthreads();
    if (lastflag) {
        float acc = 0.f;
#pragma unroll
        for (int i = 0; i < 4; ++i) {
            u32 cv = atomicAdd(&counts[t + 256*i], 0u);      // coherent read
            float p = (float)cv * (1.0f / 131072.0f);
            acc += p * logf(p + 1e-10f);
        }
#pragma unroll
        for (int off = 32; off; off >>= 1) acc += __shfl_down(acc, off, 64);
        if ((t & 63) == 0) fred[t >> 6] = acc;
        float sv = (t < 64) ? ssea[t] : 0.f;                 // prior-dispatch data
#pragma unroll
        for (int off = 32; off; off >>= 1) sv += __shfl_down(sv, off, 64);
        __syncthreads();
        if (t == 0) {
            float H = -((fred[0] + fred[1]) + (fred[2] + fred[3]));
            out[0] = 1.25f * sv * (1.0f / 8388608.0f);       // (1+BETA)*MSE
            out[8388609] = expf(H);
        }
    }
}

extern "C" void kernel_launch(void* const* d_in, const int* in_sizes, int n_in,
                              void* d_out, int out_size, void* d_ws, size_t ws_size,
                              hipStream_t stream) {
    const float* z  = (const float*)d_in[0];
    const float* cb = (const float*)d_in[1];
    float* out = (float*)d_out;
    char* ws = (char*)d_ws;
    float*    cn2    = (float*)(ws + WS_CN2);
    __bf16*   cbF    = (__bf16*)(ws + WS_CBF);
    int*      gidx   = (int*)(ws + WS_GIDX);
    unsigned* counts = (unsigned*)(ws + WS_COUNTS);
    float*    ssea   = (float*)(ws + WS_SSEA);
    unsigned* done   = (unsigned*)(ws + WS_DONE);

    prep_kernel<<<32, 256, 0, stream>>>(cb, cn2, cbF, counts, ssea, done);
    fused_kernel<<<N_TOK/128, 256, 0, stream>>>(z, cbF, cn2, cb, out, gidx, ssea);
    hist_kernel<<<32, 256, 0, stream>>>(gidx, counts, ssea, done, out);
}

// Round 2
// 137.931 us; speedup vs baseline: 1.0307x; 1.0307x over previous
//
#include <hip/hip_runtime.h>
#include <cfloat>
#include <cmath>

#define N_TOK (32*4096)                 // 131072 tokens
#define DIM   64
#define N_E   1024

typedef __attribute__((ext_vector_type(8))) __bf16 bf16x8;
typedef __attribute__((ext_vector_type(4))) float  f32x4;
typedef unsigned int u32;

// ws layout (bytes)
#define WS_CN2    0u                    // 1024 f32 (-0.5*||e||^2)           (4 KB)
#define WS_CBF    4096u                 // fragment-ordered bf16 hi+lo       (256 KB)
#define WS_GIDX   266240u               // 131072 int winner ids             (512 KB)
#define WS_COUNTS 790528u               // 1024 u32
#define WS_SSEA   794624u               // 64 f32 partial SSE cells
#define WS_DONE   794880u               // 1 u32

// Codebook -> MFMA B-fragment order (bf16 hi/lo), round-5 layout:
//   cbF[cblk*16384 + plane*8192 + ch*1024 + kf*512 + (q*16+n)*8 + j]
__global__ __launch_bounds__(256) void prep_kernel(const float* __restrict__ cb,
        float* __restrict__ cn2, __bf16* __restrict__ cbF,
        unsigned* __restrict__ counts, float* __restrict__ ssea, unsigned* __restrict__ done) {
    const int t = threadIdx.x;
    const int k = blockIdx.x * 32 + (t >> 3);        // code 0..1023
    const int oct = t & 7;
    if (t < 32) counts[blockIdx.x * 32 + t] = 0u;
    if (blockIdx.x == 0 && t < 64) ssea[t] = 0.f;
    if (blockIdx.x == 0 && t == 0) *done = 0u;

    const float4 a = *(const float4*)(cb + (size_t)k * DIM + oct * 8);
    const float4 b = *(const float4*)(cb + (size_t)k * DIM + oct * 8 + 4);
    float v[8] = {a.x,a.y,a.z,a.w,b.x,b.y,b.z,b.w};
    bf16x8 hv, lv;
    float nrm = 0.f;
#pragma unroll
    for (int j = 0; j < 8; ++j) {
        float f = v[j];
        nrm = fmaf(f, f, nrm);
        __bf16 h = (__bf16)f;
        __bf16 l = (__bf16)(f - (float)h);
        hv[j] = h; lv[j] = l;
    }
    const int cblk = k >> 7, local = k & 127;
    const int ch = local >> 4, n = local & 15;
    const int kf = oct >> 2, q = oct & 3;
    __bf16* base = cbF + (size_t)cblk * 16384 + ch * 1024 + kf * 512 + q * 128 + n * 8;
    *(bf16x8*)(base) = hv;
    *(bf16x8*)(base + 8192) = lv;
    nrm += __shfl_xor(nrm, 1, 64);
    nrm += __shfl_xor(nrm, 2, 64);
    nrm += __shfl_xor(nrm, 4, 64);
    if (oct == 0) cn2[k] = -0.5f * nrm;
}

// Round-7: NO LDS staging, NO barriers. cbF (256 KB) is L2-resident; each wave
// streams B-fragments global->VGPR with a depth-2 rotating 4-set register
// pipeline (named sets -> no scratch). Compiler's dependency waitcnt acts as a
// counted vmcnt (never drains the in-flight prefetch sets). Proven round-0
// token shape: 512 blocks x 256 tokens, 64 tokens/wave as 4 tiles (4
// independent acc chains hide MFMA dep latency).
struct BSet { bf16x8 h0, h1, l0, l1; float cn; };

__device__ __forceinline__ BSet loadB(const __bf16* __restrict__ cbF,
                                      const float* __restrict__ cn2,
                                      int ch, int lane, int n) {
    // global element offset: ch*1024 + (ch>>3)*8192 + lane*8
    const __bf16* p = cbF + (size_t)((ch << 10) + ((ch >> 3) << 13) + (lane << 3));
    BSet s;
    s.h0 = *(const bf16x8*)(p);
    s.h1 = *(const bf16x8*)(p + 512);
    s.l0 = *(const bf16x8*)(p + 8192);
    s.l1 = *(const bf16x8*)(p + 8704);
    s.cn = cn2[(ch << 4) | n];
    return s;
}

__global__ __launch_bounds__(256, 2) void fused_kernel(const float* __restrict__ z,
        const __bf16* __restrict__ cbF, const float* __restrict__ cn2,
        const float* __restrict__ cb, float* __restrict__ out,
        int* __restrict__ gidx, float* __restrict__ ssea) {
    __shared__ int lidx[256];                        // wave-local id bounce only
    const int t    = threadIdx.x;
    const int lane = t & 63;
    const int w    = t >> 6;
    const int n    = lane & 15;                      // MFMA col / code-in-chunk
    const int q    = lane >> 4;                      // k-octet selector
    const int wtok = blockIdx.x * 256 + w * 64;

    // A fragments (64 tokens/wave as 4 tiles x 2 K-halves), bf16 hi/lo in regs.
    bf16x8 ah[4][2], al[4][2];
    float pn[4];
    const float4* z4 = (const float4*)z;
#pragma unroll
    for (int tile = 0; tile < 4; ++tile) {
        int tok = wtok + tile*16 + n;
        float nrm = 0.f;
#pragma unroll
        for (int kf = 0; kf < 2; ++kf) {
            float4 p0 = z4[(size_t)tok*16 + kf*8 + q*2];
            float4 p1 = z4[(size_t)tok*16 + kf*8 + q*2 + 1];
            float v[8] = {p0.x,p0.y,p0.z,p0.w,p1.x,p1.y,p1.z,p1.w};
            bf16x8 hv, lv;
#pragma unroll
            for (int j = 0; j < 8; ++j) {
                float f = v[j];
                nrm = fmaf(f, f, nrm);
                __bf16 h = (__bf16)f;
                __bf16 l = (__bf16)(f - (float)h);
                hv[j] = h; lv[j] = l;
            }
            ah[tile][kf] = hv; al[tile][kf] = lv;
        }
        nrm += __shfl_xor(nrm, 16, 64);
        nrm += __shfl_xor(nrm, 32, 64);
        pn[tile] = nrm;
    }

    float best[16];
#pragma unroll
    for (int s = 0; s < 16; ++s) best[s] = -3.4e38f;

    // Same product order as round 0 (bitwise-identical scores).
#define COMPUTE(S, CH) do {                                                       \
        const float cnv_ = (S).cn;                                                \
        const u32 codebits_ = (u32)(((CH) << 4) | n);                             \
        _Pragma("unroll")                                                         \
        for (int tile = 0; tile < 4; ++tile) {                                    \
            f32x4 acc = {cnv_, cnv_, cnv_, cnv_};                                 \
            acc = __builtin_amdgcn_mfma_f32_16x16x32_bf16(ah[tile][0], (S).h0, acc, 0, 0, 0); \
            acc = __builtin_amdgcn_mfma_f32_16x16x32_bf16(ah[tile][1], (S).h1, acc, 0, 0, 0); \
            acc = __builtin_amdgcn_mfma_f32_16x16x32_bf16(al[tile][0], (S).h0, acc, 0, 0, 0); \
            acc = __builtin_amdgcn_mfma_f32_16x16x32_bf16(al[tile][1], (S).h1, acc, 0, 0, 0); \
            acc = __builtin_amdgcn_mfma_f32_16x16x32_bf16(ah[tile][0], (S).l0, acc, 0, 0, 0); \
            acc = __builtin_amdgcn_mfma_f32_16x16x32_bf16(ah[tile][1], (S).l1, acc, 0, 0, 0); \
            _Pragma("unroll")                                                     \
            for (int r = 0; r < 4; ++r) {                                         \
                float packed = __uint_as_float((__float_as_uint(acc[r]) & 0xFFFFFC00u) | codebits_); \
                best[tile*4 + r] = fmaxf(best[tile*4 + r], packed);               \
            }                                                                     \
        }                                                                         \
    } while (0)

    // Depth-2 software pipeline over 64 chunks of 16 codes; 4 named sets.
    BSet s0 = loadB(cbF, cn2, 0, lane, n);
    BSet s1 = loadB(cbF, cn2, 1, lane, n);
#pragma unroll 1
    for (int ch = 0; ch < 64; ch += 4) {
        BSet t0 = loadB(cbF, cn2, (ch + 2) & 63, lane, n);
        COMPUTE(s0, ch);
        BSet t1 = loadB(cbF, cn2, (ch + 3) & 63, lane, n);
        COMPUTE(s1, ch + 1);
        s0 = loadB(cbF, cn2, (ch + 4) & 63, lane, n);
        COMPUTE(t0, ch + 2);
        s1 = loadB(cbF, cn2, (ch + 5) & 63, lane, n);
        COMPUTE(t1, ch + 3);
    }
#undef COMPUTE

    // Winner reduce; ids -> wave-local LDS then plain coalesced store.
    float sse_acc = 0.f;
#pragma unroll
    for (int s = 0; s < 16; ++s) {
        float bs = best[s];
#pragma unroll
        for (int m = 8; m >= 1; m >>= 1)
            bs = fmaxf(bs, __shfl_xor(bs, m, 64));
        u32 bits = __float_as_uint(bs);
        int id = (int)(bits & 0x3FFu);
        float sc = __uint_as_float(bits & 0xFFFFFC00u);
        float nrm = __shfl(pn[s >> 2], (q << 2) | (s & 3), 64);
        if (n == 0) {
            lidx[w*64 + (s >> 2)*16 + q*4 + (s & 3)] = id;
            sse_acc += fmaf(-2.f, sc, nrm);          // d = ||z||^2 - 2*score
        }
    }
    sse_acc += __shfl_xor(sse_acc, 16, 64);
    sse_acc += __shfl_xor(sse_acc, 32, 64);
    if (lane == 0) atomicAdd(&ssea[(blockIdx.x*4 + w) & 63], sse_acc);

    int myid = lidx[w*64 + lane];                    // wave-local LDS, no barrier needed
    gidx[wtok + lane] = myid;                        // coalesced id publish

    // z_q write: wave's 64 tokens, readlane id -> independent coalesced row copies.
    const size_t obase = 1 + (size_t)wtok * DIM;
#pragma unroll
    for (int i = 0; i < 64; ++i) {
        int id = __shfl(myid, i, 64);                // compile-time lane -> v_readlane
        float qv = cb[(size_t)id * DIM + lane];
        out[obase + (size_t)i * DIM + lane] = qv;
    }
}

// Histogram from gidx via per-block LDS counts (LDS atomics), then 32 spread
// global adds per cell; last block computes entropy + loss.
__global__ __launch_bounds__(256) void hist_kernel(const int* __restrict__ gidx,
        unsigned* __restrict__ counts, const float* __restrict__ ssea,
        unsigned* __restrict__ done, float* __restrict__ out) {
    __shared__ unsigned hist[1024];
    __shared__ float fred[4];
    __shared__ u32 lastflag;
    const int t = threadIdx.x;
#pragma unroll
    for (int i = 0; i < 4; ++i) hist[t + 256*i] = 0u;
    __syncthreads();
    const int base = blockIdx.x * 4096;
#pragma unroll
    for (int i = 0; i < 16; ++i) {
        int id = gidx[base + i*256 + t];
        atomicAdd(&hist[id], 1u);
    }
    __syncthreads();
#pragma unroll
    for (int i = 0; i < 4; ++i) {
        unsigned v = hist[t + 256*i];
        if (v) atomicAdd(&counts[t + 256*i], v);
    }
    __threadfence();
    __syncthreads();
    if (t == 0) lastflag = (atomicAdd(done, 1u) == 31u) ? 1u : 0u;
    __syncthreads();
    if (lastflag) {
        float acc = 0.f;
#pragma unroll
        for (int i = 0; i < 4; ++i) {
            u32 cv = atomicAdd(&counts[t + 256*i], 0u);      // coherent read
            float p = (float)cv * (1.0f / 131072.0f);
            acc += p * logf(p + 1e-10f);
        }
#pragma unroll
        for (int off = 32; off; off >>= 1) acc += __shfl_down(acc, off, 64);
        if ((t & 63) == 0) fred[t >> 6] = acc;
        float sv = (t < 64) ? ssea[t] : 0.f;                 // prior-dispatch data
#pragma unroll
        for (int off = 32; off; off >>= 1) sv += __shfl_down(sv, off, 64);
        __syncthreads();
        if (t == 0) {
            float H = -((fred[0] + fred[1]) + (fred[2] + fred[3]));
            out[0] = 1.25f * sv * (1.0f / 8388608.0f);       // (1+BETA)*MSE
            out[8388609] = expf(H);
        }
    }
}

extern "C" void kernel_launch(void* const* d_in, const int* in_sizes, int n_in,
                              void* d_out, int out_size, void* d_ws, size_t ws_size,
                              hipStream_t stream) {
    const float* z  = (const float*)d_in[0];
    const float* cb = (const float*)d_in[1];
    float* out = (float*)d_out;
    char* ws = (char*)d_ws;
    float*    cn2    = (float*)(ws + WS_CN2);
    __bf16*   cbF    = (__bf16*)(ws + WS_CBF);
    int*      gidx   = (int*)(ws + WS_GIDX);
    unsigned* counts = (unsigned*)(ws + WS_COUNTS);
    float*    ssea   = (float*)(ws + WS_SSEA);
    unsigned* done   = (unsigned*)(ws + WS_DONE);

    prep_kernel<<<32, 256, 0, stream>>>(cb, cn2, cbF, counts, ssea, done);
    fused_kernel<<<N_TOK/256, 256, 0, stream>>>(z, cbF, cn2, cb, out, gidx, ssea);
    hist_kernel<<<32, 256, 0, stream>>>(gidx, counts, ssea, done, out);
}

// Round 3
// 125.654 us; speedup vs baseline: 1.1314x; 1.0977x over previous
//
#include <hip/hip_runtime.h>
#include <cfloat>
#include <cmath>

#define N_TOK (32*4096)                 // 131072 tokens
#define DIM   64
#define N_E   1024

typedef __attribute__((ext_vector_type(8))) _Float16 f16x8;
typedef __attribute__((ext_vector_type(4))) float    f32x4;
typedef unsigned int u32;

// ws layout (bytes)
#define WS_CN2    0u                    // 1024 f32 (-0.5*||e||^2)           (4 KB)
#define WS_CBF    4096u                 // fragment-ordered f16 (hi only)    (128 KB)
#define WS_GIDX   135168u               // 131072 int winner ids             (512 KB)
#define WS_COUNTS 659456u               // 1024 u32
#define WS_SSEA   663552u               // 64 f32 partial SSE cells
#define WS_DONE   663808u               // 1 u32

// Codebook -> MFMA B-fragment order, f16 single-plane (round-8):
//   cbF[ch*1024 + kf*512 + (q*16+n)*8 + j],  ch = 16-code chunk 0..63
// fp16 (11-bit mantissa) replaces the bf16 hi/lo 3-product scheme: cross-term
// rounding ~1.8e-6 vs score gaps ~1.2e-3; argmin flips only on near-ties whose
// z_q effect is bounded by max|e_i-e_j| = 2/1024 (already the measured absmax).
// Loss no longer depends on score precision: SSE is computed exactly in fp32
// in the epilogue.
__global__ __launch_bounds__(256) void prep_kernel(const float* __restrict__ cb,
        float* __restrict__ cn2, _Float16* __restrict__ cbF,
        unsigned* __restrict__ counts, float* __restrict__ ssea, unsigned* __restrict__ done) {
    const int t = threadIdx.x;
    const int k = blockIdx.x * 32 + (t >> 3);        // code 0..1023
    const int oct = t & 7;
    if (t < 32) counts[blockIdx.x * 32 + t] = 0u;
    if (blockIdx.x == 0 && t < 64) ssea[t] = 0.f;
    if (blockIdx.x == 0 && t == 0) *done = 0u;

    const float4 a = *(const float4*)(cb + (size_t)k * DIM + oct * 8);
    const float4 b = *(const float4*)(cb + (size_t)k * DIM + oct * 8 + 4);
    float v[8] = {a.x,a.y,a.z,a.w,b.x,b.y,b.z,b.w};
    f16x8 hv;
    float nrm = 0.f;
#pragma unroll
    for (int j = 0; j < 8; ++j) {
        float f = v[j];
        nrm = fmaf(f, f, nrm);
        hv[j] = (_Float16)f;
    }
    const int ch = k >> 4, n = k & 15;
    const int kf = oct >> 2, q = oct & 3;
    *(f16x8*)(cbF + (size_t)(ch * 1024 + kf * 512 + q * 128 + n * 8)) = hv;
    nrm += __shfl_xor(nrm, 1, 64);
    nrm += __shfl_xor(nrm, 2, 64);
    nrm += __shfl_xor(nrm, 4, 64);
    if (oct == 0) cn2[k] = -0.5f * nrm;              // exact fp32 -||e||^2/2
}

// Round-8 fused: register-streamed B (L2-resident 128 KB), no LDS staging, no
// barriers. 2 MFMAs per (tile,chunk) instead of 6. Exact fp32 SSE fused into
// the z_q gather epilogue (z rows L2-hot from prologue).
struct BSet { f16x8 h0, h1; float cn; };

__device__ __forceinline__ BSet loadB(const _Float16* __restrict__ cbF,
                                      const float* __restrict__ cn2,
                                      int ch, int lane, int n) {
    const _Float16* p = cbF + (size_t)((ch << 10) + (lane << 3));
    BSet s;
    s.h0 = *(const f16x8*)(p);
    s.h1 = *(const f16x8*)(p + 512);
    s.cn = cn2[(ch << 4) | n];
    return s;
}

__global__ __launch_bounds__(256, 2) void fused_kernel(const float* __restrict__ z,
        const _Float16* __restrict__ cbF, const float* __restrict__ cn2,
        const float* __restrict__ cb, float* __restrict__ out,
        int* __restrict__ gidx, float* __restrict__ ssea) {
    __shared__ int lidx[256];                        // wave-local id bounce only
    const int t    = threadIdx.x;
    const int lane = t & 63;
    const int w    = t >> 6;
    const int n    = lane & 15;                      // MFMA col / code-in-chunk
    const int q    = lane >> 4;                      // k-octet selector
    const int wtok = blockIdx.x * 256 + w * 64;

    // A fragments (64 tokens/wave as 4 tiles x 2 K-halves), f16 in regs.
    f16x8 ah[4][2];
    const float4* z4 = (const float4*)z;
#pragma unroll
    for (int tile = 0; tile < 4; ++tile) {
        int tok = wtok + tile*16 + n;
#pragma unroll
        for (int kf = 0; kf < 2; ++kf) {
            float4 p0 = z4[(size_t)tok*16 + kf*8 + q*2];
            float4 p1 = z4[(size_t)tok*16 + kf*8 + q*2 + 1];
            float v[8] = {p0.x,p0.y,p0.z,p0.w,p1.x,p1.y,p1.z,p1.w};
            f16x8 hv;
#pragma unroll
            for (int j = 0; j < 8; ++j) hv[j] = (_Float16)v[j];
            ah[tile][kf] = hv;
        }
    }

    float best[16];
#pragma unroll
    for (int s = 0; s < 16; ++s) best[s] = -3.4e38f;

#define COMPUTE(S, CH) do {                                                       \
        const float cnv_ = (S).cn;                                               \
        const u32 codebits_ = (u32)(((CH) << 4) | n);                            \
        _Pragma("unroll")                                                        \
        for (int tile = 0; tile < 4; ++tile) {                                   \
            f32x4 acc = {cnv_, cnv_, cnv_, cnv_};                                \
            acc = __builtin_amdgcn_mfma_f32_16x16x32_f16(ah[tile][0], (S).h0, acc, 0, 0, 0); \
            acc = __builtin_amdgcn_mfma_f32_16x16x32_f16(ah[tile][1], (S).h1, acc, 0, 0, 0); \
            _Pragma("unroll")                                                    \
            for (int r = 0; r < 4; ++r) {                                        \
                float packed = __uint_as_float((__float_as_uint(acc[r]) & 0xFFFFFC00u) | codebits_); \
                best[tile*4 + r] = fmaxf(best[tile*4 + r], packed);              \
            }                                                                    \
        }                                                                        \
    } while (0)

    // Depth-2 software pipeline over 64 chunks of 16 codes; 4 named sets.
    BSet s0 = loadB(cbF, cn2, 0, lane, n);
    BSet s1 = loadB(cbF, cn2, 1, lane, n);
#pragma unroll 1
    for (int ch = 0; ch < 64; ch += 4) {
        BSet t0 = loadB(cbF, cn2, (ch + 2) & 63, lane, n);
        COMPUTE(s0, ch);
        BSet t1 = loadB(cbF, cn2, (ch + 3) & 63, lane, n);
        COMPUTE(s1, ch + 1);
        s0 = loadB(cbF, cn2, (ch + 4) & 63, lane, n);
        COMPUTE(t0, ch + 2);
        s1 = loadB(cbF, cn2, (ch + 5) & 63, lane, n);
        COMPUTE(t1, ch + 3);
    }
#undef COMPUTE

    // Winner reduce over the 16 code-lanes per token; ids -> wave-local LDS.
#pragma unroll
    for (int s = 0; s < 16; ++s) {
        float bs = best[s];
#pragma unroll
        for (int m = 8; m >= 1; m >>= 1)
            bs = fmaxf(bs, __shfl_xor(bs, m, 64));
        if (n == 0) {
            int id = (int)(__float_as_uint(bs) & 0x3FFu);
            lidx[w*64 + (s >> 2)*16 + q*4 + (s & 3)] = id;
        }
    }

    int myid = lidx[w*64 + lane];                    // wave-local LDS, no barrier needed
    gidx[wtok + lane] = myid;                        // coalesced id publish

    // z_q write + EXACT fp32 SSE: wave's 64 tokens, readlane id -> coalesced
    // row copies; z rows re-read (L2-hot from prologue).
    const size_t obase = 1 + (size_t)wtok * DIM;
    float sse = 0.f;
#pragma unroll
    for (int i = 0; i < 64; ++i) {
        int id = __shfl(myid, i, 64);                // compile-time lane -> v_readlane
        float qv = cb[(size_t)id * DIM + lane];
        float zv = z[(size_t)(wtok + i) * DIM + lane];
        float d  = qv - zv;
        sse = fmaf(d, d, sse);
        out[obase + (size_t)i * DIM + lane] = qv;
    }
    sse += __shfl_xor(sse, 1, 64);
    sse += __shfl_xor(sse, 2, 64);
    sse += __shfl_xor(sse, 4, 64);
    sse += __shfl_xor(sse, 8, 64);
    sse += __shfl_xor(sse, 16, 64);
    sse += __shfl_xor(sse, 32, 64);
    if (lane == 0) atomicAdd(&ssea[(blockIdx.x*4 + w) & 63], sse);
}

// Histogram from gidx via per-block LDS counts (LDS atomics), then 32 spread
// global adds per cell; last block computes entropy + loss.
__global__ __launch_bounds__(256) void hist_kernel(const int* __restrict__ gidx,
        unsigned* __restrict__ counts, const float* __restrict__ ssea,
        unsigned* __restrict__ done, float* __restrict__ out) {
    __shared__ unsigned hist[1024];
    __shared__ float fred[4];
    __shared__ u32 lastflag;
    const int t = threadIdx.x;
#pragma unroll
    for (int i = 0; i < 4; ++i) hist[t + 256*i] = 0u;
    __syncthreads();
    const int base = blockIdx.x * 4096;
#pragma unroll
    for (int i = 0; i < 16; ++i) {
        int id = gidx[base + i*256 + t];
        atomicAdd(&hist[id], 1u);
    }
    __syncthreads();
#pragma unroll
    for (int i = 0; i < 4; ++i) {
        unsigned v = hist[t + 256*i];
        if (v) atomicAdd(&counts[t + 256*i], v);
    }
    __threadfence();
    __syncthreads();
    if (t == 0) lastflag = (atomicAdd(done, 1u) == 31u) ? 1u : 0u;
    __syncthreads();
    if (lastflag) {
        float acc = 0.f;
#pragma unroll
        for (int i = 0; i < 4; ++i) {
            u32 cv = atomicAdd(&counts[t + 256*i], 0u);      // coherent read
            float p = (float)cv * (1.0f / 131072.0f);
            acc += p * logf(p + 1e-10f);
        }
#pragma unroll
        for (int off = 32; off; off >>= 1) acc += __shfl_down(acc, off, 64);
        if ((t & 63) == 0) fred[t >> 6] = acc;
        float sv = (t < 64) ? ssea[t] : 0.f;                 // prior-dispatch data
#pragma unroll
        for (int off = 32; off; off >>= 1) sv += __shfl_down(sv, off, 64);
        __syncthreads();
        if (t == 0) {
            float H = -((fred[0] + fred[1]) + (fred[2] + fred[3]));
            out[0] = 1.25f * sv * (1.0f / 8388608.0f);       // (1+BETA)*MSE
            out[8388609] = expf(H);
        }
    }
}

extern "C" void kernel_launch(void* const* d_in, const int* in_sizes, int n_in,
                              void* d_out, int out_size, void* d_ws, size_t ws_size,
                              hipStream_t stream) {
    const float* z  = (const float*)d_in[0];
    const float* cb = (const float*)d_in[1];
    float* out = (float*)d_out;
    char* ws = (char*)d_ws;
    float*     cn2    = (float*)(ws + WS_CN2);
    _Float16*  cbF    = (_Float16*)(ws + WS_CBF);
    int*       gidx   = (int*)(ws + WS_GIDX);
    unsigned*  counts = (unsigned*)(ws + WS_COUNTS);
    float*     ssea   = (float*)(ws + WS_SSEA);
    unsigned*  done   = (unsigned*)(ws + WS_DONE);

    prep_kernel<<<32, 256, 0, stream>>>(cb, cn2, cbF, counts, ssea, done);
    fused_kernel<<<N_TOK/256, 256, 0, stream>>>(z, cbF, cn2, cb, out, gidx, ssea);
    hist_kernel<<<32, 256, 0, stream>>>(gidx, counts, ssea, done, out);
}